// Round 7
// baseline (1278.093 us; speedup 1.0000x reference)
//
#include <hip/hip_runtime.h>
#include <hip/hip_cooperative_groups.h>

namespace cg = cooperative_groups;

namespace {

constexpr int Bc = 4;
constexpr int Cc = 256;
constexpr int Pc = 128;
constexpr int NcT = 3136;  // true spatial size 56*56
constexpr int Np = 3200;   // padded to 25*128
constexpr int Sc = 5;
constexpr int KSn = 5;     // split-K chunks for abt (3200 = 5*640)
constexpr int KCH = 640;
constexpr float EPSc = 1e-5f;

typedef __attribute__((ext_vector_type(8))) short bf16x8;
typedef __attribute__((ext_vector_type(4))) float f32x4;
typedef __attribute__((ext_vector_type(8))) unsigned short u16x8;
typedef __attribute__((ext_vector_type(4))) unsigned short u16x4;

__device__ inline float bf2f(unsigned short u) {
    return __uint_as_float(((unsigned)u) << 16);
}
__device__ inline unsigned short f2bf(float f) {
    unsigned u = __float_as_uint(f);
    return (unsigned short)((u + 0x7FFFu + ((u >> 16) & 1u)) >> 16);
}

struct MegaArgs {
    const float* x; const float* Wt; const float* Wp; const float* Wg;
    const float* W1; const float* W2; const float* gamma; const float* beta;
    float* outp;
    float* out_sm; unsigned short* outh;
    unsigned short* U_sm; unsigned short* U_cm;
    unsigned short* agg; unsigned short* g_cmd; unsigned short* o_sm;
    float* Cpart; unsigned short* MstT;
    unsigned short* Wcomb; unsigned short* Wgh; unsigned short* Wcat;
    float* rp; float* dinv; float* ps; float* ps2;
    float* scale; float* shiftb;
};

struct GP {
    const unsigned short* A; int lda; long aB;
    const unsigned short* Bw; int ldb; long bB;
    unsigned short* outSM; int ldsm; long smB; long smSlice;
    unsigned short* outCM; long cmB;
    float* ps; float* ps2;
    int K; int kchunk;
    const float* dinv;
    const unsigned short* oin;
    const float* bnsc; const float* bnsh;
    float* resid;
};

__host__ __device__ inline GP mkU(const MegaArgs& a) {
    return GP{a.outh, 256, (long)Np * 256, a.Wcomb, 256, 0,
              a.U_sm, 256, (long)Np * 256, 0, a.U_cm, (long)256 * Np,
              a.rp, nullptr, 256, 0, nullptr, nullptr, nullptr, nullptr, nullptr};
}
__host__ __device__ inline GP mkG(const MegaArgs& a, int s) {
    return GP{a.outh, 256, (long)Np * 256, a.Wgh + (size_t)s * Pc * Cc, 256, 0,
              a.agg + 128, 256, (long)Np * 256, 0, a.g_cmd, (long)Pc * Np,
              nullptr, nullptr, 256, 0, a.dinv,
              a.o_sm, a.scale, a.shiftb, a.out_sm};
}
__host__ __device__ inline GP mkAbt(const MegaArgs& a) {
    return GP{a.g_cmd, Np, (long)Pc * Np, a.U_cm, Np, (long)256 * Np,
              (unsigned short*)a.Cpart, 256, (long)Pc * Cc, (long)Bc * Pc * Cc,
              nullptr, 0, nullptr, nullptr, Np, KCH, nullptr,
              nullptr, nullptr, nullptr, nullptr};
}
__host__ __device__ inline GP mkAg(const MegaArgs& a) {
    return GP{a.U_sm, 256, (long)Np * 256, a.MstT, 256, (long)Pc * Cc,
              a.agg, 256, (long)Np * 256, 0, nullptr, 0,
              nullptr, nullptr, 256, 0, a.dinv,
              nullptr, nullptr, nullptr, nullptr};
}
__host__ __device__ inline GP mkO(const MegaArgs& a, int s) {
    return GP{a.agg, 256, (long)Np * 256, a.Wcat + (size_t)s * Cc * 256, 256, 0,
              a.o_sm, 256, (long)Np * 256, 0, nullptr, 0,
              a.ps, a.ps2, 256, 0, nullptr,
              nullptr, nullptr, nullptr, nullptr};
}

// ---------------------------------------------------------------------------
// GEMM item: D[m][n] = sum_k A[m][k] * B[n][k]. MT=64 tile, 4 waves (64x32
// each), K-step 64, double-buffered LDS, granule swizzle phys = g ^ (row&7).
// Static LDS requirement: 2*(8192+16384) = 49152 bytes.
// ---------------------------------------------------------------------------
template <int MT, int EPI, int CMOUT, bool SPLITK, int BNSTAT, bool F32OUT,
          bool FUSEBN>
__device__ void gemm_item(char* lds, int bx, int by, int bz, int MY, const GP& p)
{
    constexpr int TBA = MT * 64 * 2;
    constexpr int TBB = 128 * 64 * 2;
    constexpr int BUF = TBA + TBB;
    constexpr int OTB = MT * 132 * 4;

    int b, kstart, kend;
    long smOff;
    if (SPLITK) {
        b = bz & 3;
        int ks = bz >> 2;
        kstart = ks * p.kchunk;
        kend = kstart + p.kchunk;
        smOff = (long)ks * p.smSlice;
    } else {
        b = bz; kstart = 0; kend = p.K; smOff = 0;
    }
    const int n0 = bx * 128;
    const int m0 = by * MT;
    const int tid = threadIdx.x;
    const int w = tid >> 6, l = tid & 63;

    const unsigned short* Ab = p.A + (size_t)b * p.aB + (size_t)m0 * p.lda;
    const unsigned short* Bb = p.Bw + (size_t)b * p.bB + (size_t)n0 * p.ldb;

    const int srow8 = tid >> 3;                 // 0..31
    const int sgran = tid & 7;
    const int sswz = (sgran ^ (srow8 & 7)) * 8; // swizzled source granule
    constexpr int AR = MT / 32;                 // A staging rounds

    constexpr int WC = 4;                       // waves along n (MT=64)
    constexpr int NB = 128 / WC / 16;           // B frags per wave = 2
    const int wc = w;

    f32x4 acc[4][NB] = {};
    float fup[AR][8];

    auto stageA = [&](int buf, int k0) {
        char* base = lds + buf * BUF;
#pragma unroll
        for (int j = 0; j < AR; ++j)
            __builtin_amdgcn_global_load_lds(
                (const __attribute__((address_space(1))) void*)
                    (Ab + (size_t)(j * 32 + srow8) * p.lda + k0 + sswz),
                (__attribute__((address_space(3))) void*)(base + j * 4096 + tid * 16),
                16, 0, 0);
    };
    auto stageB = [&](int buf, int k0) {
        char* base = lds + buf * BUF + TBA;
#pragma unroll
        for (int j = 0; j < 4; ++j)
            __builtin_amdgcn_global_load_lds(
                (const __attribute__((address_space(1))) void*)
                    (Bb + (size_t)(j * 32 + srow8) * p.ldb + k0 + sswz),
                (__attribute__((address_space(3))) void*)(base + j * 4096 + tid * 16),
                16, 0, 0);
    };
    auto fbLoad = [&](int k0) {
        const float* scp = p.bnsc + k0 + sgran * 8;
        const float* shp = p.bnsh + k0 + sgran * 8;
        float4 s0 = *(const float4*)scp, s1 = *(const float4*)(scp + 4);
        float4 h0 = *(const float4*)shp, h1 = *(const float4*)(shp + 4);
#pragma unroll
        for (int j = 0; j < AR; ++j) {
            int row = j * 32 + srow8;
            int n = m0 + row;
            size_t off = ((size_t)b * Np + n) * 256 + k0 + sgran * 8;
            if (n < NcT) {
                u16x8 ov = *(const u16x8*)(p.oin + off);
                float4 r0 = *(const float4*)(p.resid + off);
                float4 r1 = *(const float4*)(p.resid + off + 4);
                fup[j][0] = r0.x + fmaf(bf2f(ov[0]), s0.x, h0.x);
                fup[j][1] = r0.y + fmaf(bf2f(ov[1]), s0.y, h0.y);
                fup[j][2] = r0.z + fmaf(bf2f(ov[2]), s0.z, h0.z);
                fup[j][3] = r0.w + fmaf(bf2f(ov[3]), s0.w, h0.w);
                fup[j][4] = r1.x + fmaf(bf2f(ov[4]), s1.x, h1.x);
                fup[j][5] = r1.y + fmaf(bf2f(ov[5]), s1.y, h1.y);
                fup[j][6] = r1.z + fmaf(bf2f(ov[6]), s1.z, h1.z);
                fup[j][7] = r1.w + fmaf(bf2f(ov[7]), s1.w, h1.w);
            } else {
#pragma unroll
                for (int i = 0; i < 8; ++i) fup[j][i] = 0.f;
            }
            float4 w0, w1;
            w0.x = fup[j][0]; w0.y = fup[j][1]; w0.z = fup[j][2]; w0.w = fup[j][3];
            w1.x = fup[j][4]; w1.y = fup[j][5]; w1.z = fup[j][6]; w1.w = fup[j][7];
            if (n < NcT) {
                *(float4*)(p.resid + off) = w0;
                *(float4*)(p.resid + off + 4) = w1;
            }
        }
    };
    auto fbWrite = [&](int buf) {
        char* base = lds + buf * BUF;
#pragma unroll
        for (int j = 0; j < AR; ++j) {
            int row = j * 32 + srow8;
            u16x8 hv;
#pragma unroll
            for (int i = 0; i < 8; ++i) hv[i] = f2bf(fup[j][i]);
            *(u16x8*)(base + row * 128 + ((sgran ^ (row & 7)) << 4)) = hv;
        }
    };

    auto compute = [&](int buf) {
        const char* base = lds + buf * BUF;
        const int lo = l & 15, gq = l >> 4;
#pragma unroll
        for (int kh = 0; kh < 2; ++kh) {
            const int lg = kh * 4 + gq;
            bf16x8 bf[NB];
#pragma unroll
            for (int c = 0; c < NB; ++c) {
                int brow = wc * (16 * NB) + c * 16 + lo;
                bf[c] = *(const bf16x8*)(base + TBA + brow * 128 +
                                         ((lg ^ (brow & 7)) << 4));
            }
#pragma unroll
            for (int r = 0; r < 4; ++r) {
                int arow = r * 16 + lo;
                bf16x8 af = *(const bf16x8*)(base + arow * 128 +
                                             ((lg ^ (arow & 7)) << 4));
#pragma unroll
                for (int c = 0; c < NB; ++c)
                    acc[r][c] = __builtin_amdgcn_mfma_f32_16x16x32_bf16(
                        af, bf[c], acc[r][c], 0, 0, 0);
            }
        }
    };

    const int nst = (kend - kstart) >> 6;
    if constexpr (FUSEBN) {
        fbLoad(kstart);
        fbWrite(0);
        stageB(0, kstart);
        __syncthreads();
        for (int s = 0; s < nst; ++s) {
            if (s + 1 < nst) {
                fbLoad(kstart + ((s + 1) << 6));
                stageB((s + 1) & 1, kstart + ((s + 1) << 6));
            }
            compute(s & 1);
            if (s + 1 < nst) fbWrite((s + 1) & 1);
            __syncthreads();
        }
    } else {
        stageA(0, kstart);
        stageB(0, kstart);
        __syncthreads();
        for (int s = 0; s < nst; ++s) {
            if (s + 1 < nst) {
                stageA((s + 1) & 1, kstart + ((s + 1) << 6));
                stageB((s + 1) & 1, kstart + ((s + 1) << 6));
            }
            compute(s & 1);
            __syncthreads();
        }
    }

    // stage accumulators to LDS f32 [MT][132]
    float* ot = (float*)lds;
    {
        const int lo = l & 15, gq = l >> 4;
#pragma unroll
        for (int r = 0; r < 4; ++r)
#pragma unroll
            for (int c = 0; c < NB; ++c)
#pragma unroll
                for (int j = 0; j < 4; ++j) {
                    float v = acc[r][c][j];
                    if (EPI == 1) v = fmaxf(v, 0.f);
                    ot[(r * 16 + gq * 4 + j) * 132 +
                       wc * (16 * NB) + c * 16 + lo] = v;
                }
    }
    __syncthreads();

    {   // row-major store
        constexpr int TPR = 256 / MT;
        const int r = tid / TPR;
        const int c0 = (tid % TPR) * (MT / 2);
        if (F32OUT) {
            float* dst = (float*)p.outSM + (size_t)b * p.smB + smOff +
                         (size_t)(m0 + r) * p.ldsm + n0 + c0;
#pragma unroll
            for (int k = 0; k < MT / 8; ++k) {
                float4 v;
                v.x = ot[r * 132 + c0 + 4 * k + 0];
                v.y = ot[r * 132 + c0 + 4 * k + 1];
                v.z = ot[r * 132 + c0 + 4 * k + 2];
                v.w = ot[r * 132 + c0 + 4 * k + 3];
                *(float4*)(dst + 4 * k) = v;
            }
        } else {
            float sc = 1.f;
            if (EPI == 2) sc = 0.5f * p.dinv[(size_t)b * Np + m0 + r];
            unsigned short* dst = p.outSM + (size_t)b * p.smB + smOff +
                                  (size_t)(m0 + r) * p.ldsm + n0 + c0;
#pragma unroll
            for (int k = 0; k < MT / 16; ++k) {
                u16x8 o;
#pragma unroll
                for (int j = 0; j < 8; ++j) {
                    float v = ot[r * 132 + c0 + 8 * k + j];
                    if (EPI == 2) v *= sc;
                    o[j] = f2bf(v);
                }
                *(u16x8*)(dst + 8 * k) = o;
            }
        }
    }

    if (CMOUT) {   // column-major store
        const int c = tid >> 1, r0 = (tid & 1) * (MT / 2);
        const float* dv = p.dinv + (size_t)b * Np + m0 + r0;
        unsigned short* dst = p.outCM + (size_t)b * p.cmB +
                              (size_t)(n0 + c) * Np + m0 + r0;
#pragma unroll
        for (int k = 0; k < MT / 16; ++k) {
            u16x8 o;
#pragma unroll
            for (int j = 0; j < 8; ++j) {
                float v = ot[(r0 + 8 * k + j) * 132 + c];
                if (CMOUT == 2) v *= dv[8 * k + j];
                o[j] = f2bf(v);
            }
            *(u16x8*)(dst + 8 * k) = o;
        }
    }

    if (BNSTAT) {
        float* p1 = (float*)(lds + OTB);
        float* p2 = p1 + 256;
        const int col = tid & 127, half = tid >> 7;
        float s = 0.f, s2 = 0.f;
#pragma unroll
        for (int i = 0; i < MT / 2; ++i) {
            float v = ot[(half * (MT / 2) + i) * 132 + col];
            s += v;
            if (BNSTAT == 2) s2 = fmaf(v, v, s2);
        }
        p1[half * 128 + col] = s;
        if (BNSTAT == 2) p2[half * 128 + col] = s2;
        __syncthreads();
        if (tid < 128) {
            float aa = p1[tid] + p1[128 + tid];
            size_t slot = ((size_t)b * MY + by) * 256 + n0 + tid;
            p.ps[slot] = aa;
            if (BNSTAT == 2) p.ps2[slot] = p2[tid] + p2[128 + tid];
        }
    }
    __syncthreads();
}

// weight convert item (544 items x 1024 f32)
__device__ void cvtw_item(int item, const MegaArgs& a)
{
    size_t e = ((size_t)item * 256 + threadIdx.x) * 4;
    const float* src; unsigned short* dst;
    if (e < 32768)       { src = a.Wt + e;           dst = a.Wcomb + e; }
    else if (e < 65536)  { src = a.Wp + (e - 32768); dst = a.Wcomb + e; }
    else if (e < 229376) { size_t o = e - 65536;  src = a.Wg + o; dst = a.Wgh + o; }
    else if (e < 393216) { size_t o = e - 229376; src = a.W1 + o;
                           dst = a.Wcat + ((o >> 7) << 8) + (o & 127); }
    else                 { size_t o = e - 393216; src = a.W2 + o;
                           dst = a.Wcat + ((o >> 7) << 8) + 128 + (o & 127); }
    float4 v = *(const float4*)src;
    u16x4 t4;
    t4[0] = f2bf(v.x); t4[1] = f2bf(v.y); t4[2] = f2bf(v.z); t4[3] = f2bf(v.w);
    *(u16x4*)dst = t4;
}

// x[b][c][n] f32 -> out_sm[b][n][c] f32 + outh bf16 (rows >= NcT zeroed)
__device__ void xpin_item(char* ldsb, int it, const MegaArgs& a)
{
    float (*tb)[65] = (float (*)[65])ldsb;
    int nx = it % 50, cy = (it / 50) % 4, b = it / 200;
    int c0 = cy * 64, n0 = nx * 64;
    int t = threadIdx.x;
    const bool pad = (n0 >= NcT);
    if (!pad) {
        int ci = t >> 2, nb = (t & 3) * 16;
        const float* src = a.x + ((size_t)b * Cc + c0 + ci) * NcT + n0 + nb;
#pragma unroll
        for (int k = 0; k < 4; ++k) {
            float4 v = *(const float4*)(src + 4 * k);
            tb[ci][nb + 4 * k + 0] = v.x; tb[ci][nb + 4 * k + 1] = v.y;
            tb[ci][nb + 4 * k + 2] = v.z; tb[ci][nb + 4 * k + 3] = v.w;
        }
    }
    __syncthreads();
    int r = t >> 2, cb = (t & 3) * 16;
    size_t off = ((size_t)b * Np + n0 + r) * 256 + c0 + cb;
    float vv[16];
#pragma unroll
    for (int j = 0; j < 16; ++j) vv[j] = pad ? 0.f : tb[cb + j][r];
    float* dst = a.out_sm + off;
#pragma unroll
    for (int k = 0; k < 4; ++k) {
        float4 v; v.x = vv[4*k]; v.y = vv[4*k+1]; v.z = vv[4*k+2]; v.w = vv[4*k+3];
        *(float4*)(dst + 4 * k) = v;
    }
    u16x8 h1, h2;
#pragma unroll
    for (int j = 0; j < 8; ++j) { h1[j] = f2bf(vv[j]); h2[j] = f2bf(vv[8 + j]); }
    unsigned short* dh = a.outh + off;
    *(u16x8*)dh = h1;
    *(u16x8*)(dh + 8) = h2;
    __syncthreads();
}

// dinv[b][i] = d>0 ? rsqrt(d) : 0   (rp has 50 groups per batch)
__device__ void dinv_item(char* ldsb, int ix, int b, const MegaArgs& a)
{
    float* rsl = (float*)ldsb;
    int tid = threadIdx.x;
    float s = 0.f;
    for (int j = 0; j < 50; ++j) s += a.rp[((size_t)b * 50 + j) * 256 + tid];
    rsl[tid ^ 128] = s;
    __syncthreads();
    int i = ix * 256 + tid;
    if (i < Np) {
        const unsigned short* row = a.U_sm + ((size_t)b * Np + i) * 256;
        float acc = 0.f;
        for (int q0 = 0; q0 < 256; q0 += 8) {
            u16x8 v = *(const u16x8*)(row + q0);
#pragma unroll
            for (int j = 0; j < 8; ++j) acc = fmaf(bf2f(v[j]), rsl[q0 + j], acc);
        }
        float d = 0.5f * acc;
        a.dinv[(size_t)b * Np + i] = d > 0.f ? rsqrtf(d) : 0.f;
    }
    __syncthreads();
}

// MstT[b][p][q] = sum_ks Cpart_f32[ks][b][p][q^128]  -> bf16
__device__ void redmst_item(int bid, const MegaArgs& a)
{
    int e8 = bid * 256 + threadIdx.x;    // 16384 total
    int bp = e8 >> 5, qc = e8 & 31;
    size_t dstOff = ((size_t)bp * 32 + qc) * 8;
    size_t srcOff = ((size_t)bp * 32 + (qc ^ 16)) * 8;
    float4 s0 = {0.f, 0.f, 0.f, 0.f}, s1 = {0.f, 0.f, 0.f, 0.f};
    for (int ks = 0; ks < KSn; ++ks) {
        const float* base = a.Cpart + (size_t)ks * (Bc * Pc * Cc) + srcOff;
        float4 v0 = *(const float4*)base;
        float4 v1 = *(const float4*)(base + 4);
        s0.x += v0.x; s0.y += v0.y; s0.z += v0.z; s0.w += v0.w;
        s1.x += v1.x; s1.y += v1.y; s1.z += v1.z; s1.w += v1.w;
    }
    u16x8 o;
    o[0] = f2bf(s0.x); o[1] = f2bf(s0.y); o[2] = f2bf(s0.z); o[3] = f2bf(s0.w);
    o[4] = f2bf(s1.x); o[5] = f2bf(s1.y); o[6] = f2bf(s1.z); o[7] = f2bf(s1.w);
    *(u16x8*)(a.MstT + dstOff) = o;
}

// BN finalize: 16 items x 16 channels; 200 partial groups
__device__ void bnfin_item(char* ldsb, int bid, const MegaArgs& a, int s)
{
    float* l1 = (float*)ldsb;
    float* l2 = l1 + 256;
    const float* gamma = a.gamma + s * Cc;
    const float* beta = a.beta + s * Cc;
    int t = threadIdx.x;
    int c = bid * 16 + (t & 15);
    int gl = t >> 4;
    float aa = 0.f, a2 = 0.f;
    for (int g = gl; g < 200; g += 16) {
        aa += a.ps[(size_t)g * 256 + c];
        a2 += a.ps2[(size_t)g * 256 + c];
    }
    l1[t] = aa; l2[t] = a2;
    __syncthreads();
    if (gl == 0) {
#pragma unroll
        for (int j = 1; j < 16; ++j) {
            aa += l1[j * 16 + (t & 15)];
            a2 += l2[j * 16 + (t & 15)];
        }
        const float inv = 1.f / (float)(Bc * NcT);
        float mean = aa * inv;
        float var = a2 * inv - mean * mean;
        float sc = gamma[c] * rsqrtf(var + EPSc);
        a.scale[c] = sc;
        a.shiftb[c] = beta[c] - mean * sc;
    }
    __syncthreads();
}

// d_out[b][c][n] = transpose(out_sm + BN(o_sm))
__device__ void xpoutbn_item(char* ldsb, int it, const MegaArgs& a)
{
    float (*tb)[65] = (float (*)[65])ldsb;
    float* lsc = (float*)(ldsb + 64 * 65 * 4);
    float* lsh = lsc + 64;
    int nx = it % 49, cy = (it / 49) % 4, b = it / 196;
    int c0 = cy * 64, n0 = nx * 64;
    int t = threadIdx.x;
    if (t < 64) { lsc[t] = a.scale[c0 + t]; lsh[t] = a.shiftb[c0 + t]; }
    __syncthreads();
    {
        int r = t >> 2, cb = (t & 3) * 16;
        size_t off = ((size_t)b * Np + n0 + r) * 256 + c0 + cb;
#pragma unroll
        for (int k = 0; k < 2; ++k) {
            float4 a0 = *(const float4*)(a.out_sm + off + 8 * k);
            float4 a1 = *(const float4*)(a.out_sm + off + 8 * k + 4);
            u16x8 ov = *(const u16x8*)(a.o_sm + off + 8 * k);
            tb[r][cb + 8*k + 0] = a0.x + fmaf(bf2f(ov[0]), lsc[cb + 8*k + 0], lsh[cb + 8*k + 0]);
            tb[r][cb + 8*k + 1] = a0.y + fmaf(bf2f(ov[1]), lsc[cb + 8*k + 1], lsh[cb + 8*k + 1]);
            tb[r][cb + 8*k + 2] = a0.z + fmaf(bf2f(ov[2]), lsc[cb + 8*k + 2], lsh[cb + 8*k + 2]);
            tb[r][cb + 8*k + 3] = a0.w + fmaf(bf2f(ov[3]), lsc[cb + 8*k + 3], lsh[cb + 8*k + 3]);
            tb[r][cb + 8*k + 4] = a1.x + fmaf(bf2f(ov[4]), lsc[cb + 8*k + 4], lsh[cb + 8*k + 4]);
            tb[r][cb + 8*k + 5] = a1.y + fmaf(bf2f(ov[5]), lsc[cb + 8*k + 5], lsh[cb + 8*k + 5]);
            tb[r][cb + 8*k + 6] = a1.z + fmaf(bf2f(ov[6]), lsc[cb + 8*k + 6], lsh[cb + 8*k + 6]);
            tb[r][cb + 8*k + 7] = a1.w + fmaf(bf2f(ov[7]), lsc[cb + 8*k + 7], lsh[cb + 8*k + 7]);
        }
    }
    __syncthreads();
    {
        int c = t >> 2, rb = (t & 3) * 16;
        float vv[16];
#pragma unroll
        for (int j = 0; j < 16; ++j) vv[j] = tb[rb + j][c];
        float* dst = a.outp + ((size_t)b * Cc + c0 + c) * NcT + n0 + rb;
#pragma unroll
        for (int k = 0; k < 4; ++k) {
            float4 v; v.x = vv[4*k]; v.y = vv[4*k+1]; v.z = vv[4*k+2]; v.w = vv[4*k+3];
            *(float4*)(dst + 4 * k) = v;
        }
    }
    __syncthreads();
}

// ---------------------------------------------------------------------------
// Cooperative mega-kernel (static LDS 49152 B < 64 KB for coop validation)
// ---------------------------------------------------------------------------
__global__ __launch_bounds__(256) void mega(MegaArgs a)
{
    __shared__ __align__(16) char lds[49152];
    cg::grid_group grid = cg::this_grid();
    const int bid = blockIdx.x;
    const int nb = gridDim.x;

    // P0: weight convert (544) + input transpose (800)
    for (int it = bid; it < 1344; it += nb) {
        if (it < 544) cvtw_item(it, a);
        else          xpin_item(lds, it - 544, a);
    }
    grid.sync();

    // P1: U = relu([Wt;Wp] @ x) + col-major copy + col sums (400 items)
    {
        GP p = mkU(a);
        for (int it = bid; it < 400; it += nb)
            gemm_item<64, 1, 1, false, 1, false, false>(
                lds, it & 1, (it >> 1) % 50, it / 100, 50, p);
    }
    grid.sync();

    // P2: dinv (52 items)
    for (int it = bid; it < 52; it += nb)
        dinv_item(lds, it % 13, it / 13, a);
    grid.sync();

    for (int s = 0; s < Sc; ++s) {
        // P3: g = Wg[s] @ out (FUSEBN applies prev stage BN to residual)
        {
            GP p = mkG(a, s);
            if (s == 0) {
                for (int it = bid; it < 200; it += nb)
                    gemm_item<64, 0, 2, false, 0, false, false>(
                        lds, 0, it % 50, it / 50, 50, p);
            } else {
                for (int it = bid; it < 200; it += nb)
                    gemm_item<64, 0, 2, false, 0, false, true>(
                        lds, 0, it % 50, it / 50, 50, p);
            }
        }
        grid.sync();
        // P4: abt split-K partials (80 items)
        {
            GP p = mkAbt(a);
            for (int it = bid; it < 80; it += nb)
                gemm_item<64, 0, 0, true, 0, true, false>(
                    lds, it & 1, (it >> 1) & 1, it >> 2, 2, p);
        }
        grid.sync();
        // P5: reduce split-K -> MstT (64 items)
        for (int it = bid; it < 64; it += nb) redmst_item(it, a);
        grid.sync();
        // P6: ag = 0.5*dinv ⊙ (U_sm @ MstT^T) (200 items)
        {
            GP p = mkAg(a);
            for (int it = bid; it < 200; it += nb)
                gemm_item<64, 2, 0, false, 0, false, false>(
                    lds, 0, it % 50, it / 50, 50, p);
        }
        grid.sync();
        // P7: o = Wcat[s] @ [ag; g] + BN partial stats (400 items)
        {
            GP p = mkO(a, s);
            for (int it = bid; it < 400; it += nb)
                gemm_item<64, 0, 0, false, 2, false, false>(
                    lds, it & 1, (it >> 1) % 50, it / 100, 50, p);
        }
        grid.sync();
        // P8: BN finalize (16 items)
        for (int it = bid; it < 16; it += nb) bnfin_item(lds, it, a, s);
        grid.sync();
    }

    // P9: d_out = transpose(out_sm + BN(o_sm)) (784 items)
    for (int it = bid; it < 784; it += nb) xpoutbn_item(lds, it, a);
}

// ---------------------------------------------------------------------------
// Fallback wrappers (separate kernels; identical device functions)
// ---------------------------------------------------------------------------
__global__ __launch_bounds__(256) void cvtw_glb(MegaArgs a) {
    cvtw_item(blockIdx.x, a);
}
__global__ __launch_bounds__(256) void xpin_glb(MegaArgs a) {
    __shared__ __align__(16) char l[16640];
    xpin_item(l, blockIdx.x, a);
}
template <int EPI, int CMOUT, bool SPLITK, int BNSTAT, bool F32OUT, bool FUSEBN>
__global__ __launch_bounds__(256) void gemm_glb(GP p) {
    __shared__ __align__(16) char l[49152];
    gemm_item<64, EPI, CMOUT, SPLITK, BNSTAT, F32OUT, FUSEBN>(
        l, blockIdx.x, blockIdx.y, blockIdx.z, (int)gridDim.y, p);
}
__global__ __launch_bounds__(256) void dinv_glb(MegaArgs a) {
    __shared__ __align__(16) char l[1024];
    dinv_item(l, blockIdx.x, blockIdx.y, a);
}
__global__ __launch_bounds__(256) void redmst_glb(MegaArgs a) {
    redmst_item(blockIdx.x, a);
}
__global__ __launch_bounds__(256) void bnfin_glb(MegaArgs a, int s) {
    __shared__ __align__(16) char l[2048];
    bnfin_item(l, blockIdx.x, a, s);
}
__global__ __launch_bounds__(256) void xpoutbn_glb(MegaArgs a) {
    __shared__ __align__(16) char l[17152];
    xpoutbn_item(l, blockIdx.x, a);
}

}  // namespace

extern "C" void kernel_launch(void* const* d_in, const int* in_sizes, int n_in,
                              void* d_out, int out_size, void* d_ws, size_t ws_size,
                              hipStream_t stream) {
    char* p = (char*)d_ws;
    auto alloc = [&](size_t bytes) { char* r = p; p += (bytes + 255) & ~(size_t)255; return r; };

    MegaArgs a;
    a.x     = (const float*)d_in[0];
    a.Wt    = (const float*)d_in[1];
    a.Wp    = (const float*)d_in[2];
    a.Wg    = (const float*)d_in[3];
    a.W1    = (const float*)d_in[4];
    a.W2    = (const float*)d_in[5];
    a.gamma = (const float*)d_in[6];
    a.beta  = (const float*)d_in[7];
    a.outp  = (float*)d_out;

    a.out_sm = (float*)         alloc((size_t)Bc * Np * 256 * 4);
    a.outh   = (unsigned short*)alloc((size_t)Bc * Np * 256 * 2);
    a.U_sm   = (unsigned short*)alloc((size_t)Bc * Np * 256 * 2);
    a.U_cm   = (unsigned short*)alloc((size_t)Bc * 256 * Np * 2);
    a.agg    = (unsigned short*)alloc((size_t)Bc * Np * 256 * 2);
    a.g_cmd  = (unsigned short*)alloc((size_t)Bc * Pc * Np * 2);
    a.o_sm   = (unsigned short*)alloc((size_t)Bc * Np * 256 * 2);
    a.Cpart  = (float*)         alloc((size_t)KSn * Bc * Pc * Cc * 4);
    a.MstT   = (unsigned short*)alloc((size_t)Bc * Pc * Cc * 2);
    a.Wcomb  = (unsigned short*)alloc((size_t)Cc * Cc * 2);
    a.Wgh    = (unsigned short*)alloc((size_t)Sc * Pc * Cc * 2);
    a.Wcat   = (unsigned short*)alloc((size_t)Sc * Cc * 256 * 2);
    a.rp     = (float*)         alloc((size_t)200 * 256 * 4);
    a.dinv   = (float*)         alloc((size_t)Bc * Np * 4);
    a.ps     = (float*)         alloc((size_t)200 * 256 * 4);
    a.ps2    = (float*)         alloc((size_t)200 * 256 * 4);
    a.scale  = (float*)         alloc(256 * 4);
    a.shiftb = (float*)         alloc(256 * 4);

    // try the cooperative mega-kernel first
    hipError_t err = hipErrorUnknown;
    int maxB = 0;
    hipError_t q = hipOccupancyMaxActiveBlocksPerMultiprocessor(
        &maxB, (const void*)mega, 256, 0);
    if (q == hipSuccess && maxB >= 1) {
        int bpc = maxB >= 2 ? 2 : 1;
        void* kargs[] = { (void*)&a };
        err = hipLaunchCooperativeKernel((const void*)mega, dim3(256 * bpc),
                                         dim3(256), kargs, 0, stream);
    }
    if (err != hipSuccess) {
        // fallback: separate kernels (same math)
        dim3 blk(256);
        cvtw_glb<<<544, blk, 0, stream>>>(a);
        xpin_glb<<<800, blk, 0, stream>>>(a);
        gemm_glb<1, 1, false, 1, false, false><<<dim3(2, 50, 4), blk, 0, stream>>>(mkU(a));
        dinv_glb<<<dim3(13, 4), blk, 0, stream>>>(a);
        for (int s = 0; s < Sc; ++s) {
            if (s == 0)
                gemm_glb<0, 2, false, 0, false, false><<<dim3(1, 50, 4), blk, 0, stream>>>(mkG(a, 0));
            else
                gemm_glb<0, 2, false, 0, false, true><<<dim3(1, 50, 4), blk, 0, stream>>>(mkG(a, s));
            gemm_glb<0, 0, true, 0, true, false><<<dim3(2, 2, 20), blk, 0, stream>>>(mkAbt(a));
            redmst_glb<<<64, blk, 0, stream>>>(a);
            gemm_glb<2, 0, false, 0, false, false><<<dim3(1, 50, 4), blk, 0, stream>>>(mkAg(a));
            gemm_glb<0, 0, false, 2, false, false><<<dim3(2, 50, 4), blk, 0, stream>>>(mkO(a, s));
            bnfin_glb<<<16, blk, 0, stream>>>(a, s);
        }
        xpoutbn_glb<<<784, blk, 0, stream>>>(a);
    }
}

// Round 9
// 271.041 us; speedup vs baseline: 4.7155x; 4.7155x over previous
//
#include <hip/hip_runtime.h>

namespace {

constexpr int Bc = 4;
constexpr int Cc = 256;
constexpr int Pc = 128;
constexpr int NcT = 3136;  // true spatial size 56*56
constexpr int Np = 3200;   // padded to 25*128
constexpr int Sc = 5;
constexpr int KSn = 5;     // split-K chunks for abt (3200 = 5*640)
constexpr int KCH = 640;
constexpr float EPSc = 1e-5f;

typedef __attribute__((ext_vector_type(8))) short bf16x8;
typedef __attribute__((ext_vector_type(4))) float f32x4;
typedef __attribute__((ext_vector_type(8))) unsigned short u16x8;
typedef __attribute__((ext_vector_type(4))) unsigned short u16x4;

__device__ inline float bf2f(unsigned short u) {
    return __uint_as_float(((unsigned)u) << 16);
}
__device__ inline unsigned short f2bf(float f) {
    unsigned u = __float_as_uint(f);
    return (unsigned short)((u + 0x7FFFu + ((u >> 16) & 1u)) >> 16);
}

struct GP {
    const unsigned short* A; int lda; long aB; long aSl;
    const unsigned short* Bw; int ldb; long bB; long bSl;
    const unsigned short* A2; int lda2; long aB2;
    const unsigned short* B2; int ldb2; long bB2;
    int K; int K2; int nsl; int kchunk;
    unsigned short* outSM; int ldsm; long smB; long smSlice;
    unsigned short* outCM; long cmB;
    float* ps; float* ps2;
    const float* dinv;
    const unsigned short* oin; const float* bnsc; const float* bnsh;
    float* resid;
};

// ---------------------------------------------------------------------------
// MFMA GEMM: D[m][n] = sum over slices/loops of A[m][k]*B[n][k] (K-contig).
// Tile MT(m) x 128(n), 4 waves, K-step 64, double-buffered LDS via
// global_load_lds(16B), granule swizzle phys = g ^ (row&7).
// EPI: 0 none, 1 relu.  CMOUT: 0 none, 1 plain col-major, 2 col-major*dinv[m]
// SPLITK: z=ks*4+b, K range [ks*kchunk,+kchunk), out += ks*smSlice
// BNSTAT: 1 col sums->ps, 2 +sumsq->ps2.  FUSEBN: A = resid + BN(oin) on the
// fly (resid updated).  XORM: row-major store to row (m0^128)+r.
// DUALK: second accumulation loop over (A2,B2,K2).
// ---------------------------------------------------------------------------
template <int MT, int EPI, int CMOUT, bool SPLITK, int BNSTAT, bool FUSEBN,
          bool XORM, bool DUALK>
__global__ __launch_bounds__(256) void mgemm(GP p)
{
    constexpr int TBA = MT * 64 * 2;
    constexpr int TBB = 128 * 64 * 2;
    constexpr int BUF = TBA + TBB;
    constexpr int OTB = MT * 132 * 4;
    constexpr int LDSZ = (2 * BUF > OTB + 2048) ? 2 * BUF : (OTB + 2048);
    __shared__ __align__(16) char lds[LDSZ];

    int b, kstart;
    long smOff;
    if (SPLITK) {
        b = blockIdx.z & 3;
        int ks = blockIdx.z >> 2;
        kstart = ks * p.kchunk;
        smOff = (long)ks * p.smSlice;
    } else {
        b = blockIdx.z; kstart = 0; smOff = 0;
    }
    const int n0 = blockIdx.x * 128;
    const int m0 = blockIdx.y * MT;
    const int tid = threadIdx.x;
    const int w = tid >> 6, l = tid & 63;

    const unsigned short* Ab = p.A + (size_t)b * p.aB + (size_t)m0 * p.lda;
    const unsigned short* Bb = p.Bw + (size_t)b * p.bB + (size_t)n0 * p.ldb;

    const int srow8 = tid >> 3;                  // 0..31
    const int sgran = tid & 7;
    const int sswz = (sgran ^ (srow8 & 7)) * 8;  // swizzled source granule
    constexpr int AR = MT / 32;                  // A staging rounds

    constexpr int WC = (MT == 128) ? 2 : 4;      // waves along n
    constexpr int NB = 128 / WC / 16;            // B frags per wave
    const int wr = w / WC, wc = w % WC;

    f32x4 acc[4][NB] = {};
    float fup[AR][8];

    auto stage1 = [&](int buf, int sl, int k0) {
        char* base = lds + buf * BUF;
        const unsigned short* As = Ab + (size_t)sl * p.aSl + k0 + sswz;
#pragma unroll
        for (int j = 0; j < AR; ++j)
            __builtin_amdgcn_global_load_lds(
                (const __attribute__((address_space(1))) void*)
                    (As + (size_t)(j * 32 + srow8) * p.lda),
                (__attribute__((address_space(3))) void*)(base + j * 4096 + tid * 16),
                16, 0, 0);
        const unsigned short* Bs = Bb + (size_t)sl * p.bSl + k0 + sswz;
#pragma unroll
        for (int j = 0; j < 4; ++j)
            __builtin_amdgcn_global_load_lds(
                (const __attribute__((address_space(1))) void*)
                    (Bs + (size_t)(j * 32 + srow8) * p.ldb),
                (__attribute__((address_space(3))) void*)(base + TBA + j * 4096 + tid * 16),
                16, 0, 0);
    };

    auto stageB1 = [&](int buf, int k0) {
        char* base = lds + buf * BUF + TBA;
        const unsigned short* Bs = Bb + k0 + sswz;
#pragma unroll
        for (int j = 0; j < 4; ++j)
            __builtin_amdgcn_global_load_lds(
                (const __attribute__((address_space(1))) void*)
                    (Bs + (size_t)(j * 32 + srow8) * p.ldb),
                (__attribute__((address_space(3))) void*)(base + j * 4096 + tid * 16),
                16, 0, 0);
    };

    auto fbLoad = [&](int k0) {
        const float* scp = p.bnsc + k0 + sgran * 8;
        const float* shp = p.bnsh + k0 + sgran * 8;
        float4 s0 = *(const float4*)scp, s1 = *(const float4*)(scp + 4);
        float4 h0 = *(const float4*)shp, h1 = *(const float4*)(shp + 4);
#pragma unroll
        for (int j = 0; j < AR; ++j) {
            int row = j * 32 + srow8;
            int n = m0 + row;
            size_t off = ((size_t)b * Np + n) * 256 + k0 + sgran * 8;
            if (n < NcT) {
                u16x8 ov = *(const u16x8*)(p.oin + off);
                float4 r0 = *(const float4*)(p.resid + off);
                float4 r1 = *(const float4*)(p.resid + off + 4);
                fup[j][0] = r0.x + fmaf(bf2f(ov[0]), s0.x, h0.x);
                fup[j][1] = r0.y + fmaf(bf2f(ov[1]), s0.y, h0.y);
                fup[j][2] = r0.z + fmaf(bf2f(ov[2]), s0.z, h0.z);
                fup[j][3] = r0.w + fmaf(bf2f(ov[3]), s0.w, h0.w);
                fup[j][4] = r1.x + fmaf(bf2f(ov[4]), s1.x, h1.x);
                fup[j][5] = r1.y + fmaf(bf2f(ov[5]), s1.y, h1.y);
                fup[j][6] = r1.z + fmaf(bf2f(ov[6]), s1.z, h1.z);
                fup[j][7] = r1.w + fmaf(bf2f(ov[7]), s1.w, h1.w);
                float4 w0, w1;
                w0.x = fup[j][0]; w0.y = fup[j][1]; w0.z = fup[j][2]; w0.w = fup[j][3];
                w1.x = fup[j][4]; w1.y = fup[j][5]; w1.z = fup[j][6]; w1.w = fup[j][7];
                *(float4*)(p.resid + off) = w0;
                *(float4*)(p.resid + off + 4) = w1;
            } else {
#pragma unroll
                for (int i = 0; i < 8; ++i) fup[j][i] = 0.f;
            }
        }
    };
    auto fbWrite = [&](int buf) {
        char* base = lds + buf * BUF;
#pragma unroll
        for (int j = 0; j < AR; ++j) {
            int row = j * 32 + srow8;
            u16x8 hv;
#pragma unroll
            for (int i = 0; i < 8; ++i) hv[i] = f2bf(fup[j][i]);
            *(u16x8*)(base + row * 128 + ((sgran ^ (row & 7)) << 4)) = hv;
        }
    };

    auto compute = [&](int buf) {
        const char* base = lds + buf * BUF;
        const int lo = l & 15, gq = l >> 4;
#pragma unroll
        for (int kh = 0; kh < 2; ++kh) {
            const int lg = kh * 4 + gq;
            bf16x8 bf[NB];
#pragma unroll
            for (int c = 0; c < NB; ++c) {
                int brow = wc * (16 * NB) + c * 16 + lo;
                bf[c] = *(const bf16x8*)(base + TBA + brow * 128 +
                                         ((lg ^ (brow & 7)) << 4));
            }
#pragma unroll
            for (int r = 0; r < 4; ++r) {
                int arow = wr * 64 + r * 16 + lo;
                bf16x8 af = *(const bf16x8*)(base + arow * 128 +
                                             ((lg ^ (arow & 7)) << 4));
#pragma unroll
                for (int c = 0; c < NB; ++c)
                    acc[r][c] = __builtin_amdgcn_mfma_f32_16x16x32_bf16(
                        af, bf[c], acc[r][c], 0, 0, 0);
            }
        }
    };

    if constexpr (FUSEBN) {
        const int nst = p.K >> 6;    // nsl==1, no DUALK in this mode
        fbLoad(kstart);
        fbWrite(0);
        stageB1(0, kstart);
        __syncthreads();
        for (int s = 0; s < nst; ++s) {
            if (s + 1 < nst) {
                fbLoad(kstart + ((s + 1) << 6));
                stageB1((s + 1) & 1, kstart + ((s + 1) << 6));
            }
            compute(s & 1);
            if (s + 1 < nst) fbWrite((s + 1) & 1);
            __syncthreads();
        }
    } else {
        const int nsteps1 = (SPLITK ? p.kchunk : p.K) >> 6;
        const int spl2 = DUALK ? (p.K2 >> 6) : 0;
        const int tot = p.nsl * nsteps1 + spl2;

        // second-loop staging (only instantiated for DUALK)
        const unsigned short* Ab2 = DUALK ?
            (p.A2 + (size_t)b * p.aB2 + (size_t)m0 * p.lda2) : nullptr;
        const unsigned short* Bb2 = DUALK ?
            (p.B2 + (size_t)b * p.bB2 + (size_t)n0 * p.ldb2) : nullptr;
        auto stage2 = [&](int buf, int k0) {
            if constexpr (DUALK) {
                char* base = lds + buf * BUF;
                const unsigned short* As = Ab2 + k0 + sswz;
#pragma unroll
                for (int j = 0; j < AR; ++j)
                    __builtin_amdgcn_global_load_lds(
                        (const __attribute__((address_space(1))) void*)
                            (As + (size_t)(j * 32 + srow8) * p.lda2),
                        (__attribute__((address_space(3))) void*)(base + j * 4096 + tid * 16),
                        16, 0, 0);
                const unsigned short* Bs = Bb2 + k0 + sswz;
#pragma unroll
                for (int j = 0; j < 4; ++j)
                    __builtin_amdgcn_global_load_lds(
                        (const __attribute__((address_space(1))) void*)
                            (Bs + (size_t)(j * 32 + srow8) * p.ldb2),
                        (__attribute__((address_space(3))) void*)(base + TBA + j * 4096 + tid * 16),
                        16, 0, 0);
            }
        };

        stage1(0, 0, kstart);
        __syncthreads();
        int sl = 0, st = 1;
        if (st == nsteps1) { st = 0; sl = 1; }
        for (int gs = 0; gs < tot; ++gs) {
            if (gs + 1 < tot) {
                if (sl < p.nsl) stage1((gs + 1) & 1, sl, kstart + (st << 6));
                else            stage2((gs + 1) & 1, st << 6);
                ++st;
                int lim = (sl < p.nsl) ? nsteps1 : spl2;
                if (st == lim) { st = 0; ++sl; }
            }
            compute(gs & 1);
            __syncthreads();
        }
    }

    // stage accumulators to LDS f32 [MT][132]
    float* ot = (float*)lds;
    {
        const int lo = l & 15, gq = l >> 4;
#pragma unroll
        for (int r = 0; r < 4; ++r)
#pragma unroll
            for (int c = 0; c < NB; ++c)
#pragma unroll
                for (int j = 0; j < 4; ++j) {
                    float v = acc[r][c][j];
                    if (EPI == 1) v = fmaxf(v, 0.f);
                    ot[(wr * 64 + r * 16 + gq * 4 + j) * 132 +
                       wc * (16 * NB) + c * 16 + lo] = v;
                }
    }
    __syncthreads();

    {   // row-major store
        constexpr int TPR = 256 / MT;
        const int r = tid / TPR;
        const int c0 = (tid % TPR) * (MT / 2);
        const int m0s = XORM ? (m0 ^ 128) : m0;
        unsigned short* dst = p.outSM + (size_t)b * p.smB + smOff +
                              (size_t)(m0s + r) * p.ldsm + n0 + c0;
#pragma unroll
        for (int k = 0; k < MT / 16; ++k) {
            u16x8 o;
#pragma unroll
            for (int j = 0; j < 8; ++j) o[j] = f2bf(ot[r * 132 + c0 + 8 * k + j]);
            *(u16x8*)(dst + 8 * k) = o;
        }
    }

    if (CMOUT) {   // column-major store
        const int c = tid >> 1, r0 = (tid & 1) * (MT / 2);
        const float* dv = p.dinv + (size_t)b * Np + m0 + r0;
        unsigned short* dst = p.outCM + (size_t)b * p.cmB +
                              (size_t)(n0 + c) * Np + m0 + r0;
#pragma unroll
        for (int k = 0; k < MT / 16; ++k) {
            u16x8 o;
#pragma unroll
            for (int j = 0; j < 8; ++j) {
                float v = ot[(r0 + 8 * k + j) * 132 + c];
                if (CMOUT == 2) v *= dv[8 * k + j];
                o[j] = f2bf(v);
            }
            *(u16x8*)(dst + 8 * k) = o;
        }
    }

    if (BNSTAT) {
        float* p1 = (float*)(lds + OTB);
        float* p2 = p1 + 256;
        const int col = tid & 127, half = tid >> 7;
        float s = 0.f, s2 = 0.f;
#pragma unroll
        for (int i = 0; i < MT / 2; ++i) {
            float v = ot[(half * (MT / 2) + i) * 132 + col];
            s += v;
            if (BNSTAT == 2) s2 = fmaf(v, v, s2);
        }
        p1[half * 128 + col] = s;
        if (BNSTAT == 2) p2[half * 128 + col] = s2;
        __syncthreads();
        if (tid < 128) {
            float aa = p1[tid] + p1[128 + tid];
            size_t slot = ((size_t)b * gridDim.y + blockIdx.y) * 256 + n0 + tid;
            p.ps[slot] = aa;
            if (BNSTAT == 2) p.ps2[slot] = p2[tid] + p2[128 + tid];
        }
    }
}

// ---------------------------------------------------------------------------
// prep: weight f32->bf16 (544 items) + input transpose (800 items)
// ---------------------------------------------------------------------------
__global__ __launch_bounds__(256) void prep_k(
    const float* __restrict__ x, const float* __restrict__ Wt,
    const float* __restrict__ Wp, const float* __restrict__ Wg,
    const float* __restrict__ W1, const float* __restrict__ W2,
    unsigned short* __restrict__ Wcomb, unsigned short* __restrict__ Wgh,
    unsigned short* __restrict__ W1h, unsigned short* __restrict__ W2h,
    float* __restrict__ out_sm, unsigned short* __restrict__ outh)
{
    __shared__ float tb[64][65];
    int item = blockIdx.x;
    int t = threadIdx.x;
    if (item < 544) {
        size_t e = ((size_t)item * 256 + t) * 4;
        const float* src; unsigned short* dst;
        if (e < 32768)       { src = Wt + e;           dst = Wcomb + e; }
        else if (e < 65536)  { src = Wp + (e - 32768); dst = Wcomb + e; }
        else if (e < 229376) { size_t o = e - 65536;  src = Wg + o; dst = Wgh + o; }
        else if (e < 393216) { size_t o = e - 229376; src = W1 + o; dst = W1h + o; }
        else                 { size_t o = e - 393216; src = W2 + o; dst = W2h + o; }
        float4 v = *(const float4*)src;
        u16x4 t4;
        t4[0] = f2bf(v.x); t4[1] = f2bf(v.y); t4[2] = f2bf(v.z); t4[3] = f2bf(v.w);
        *(u16x4*)dst = t4;
        return;
    }
    int it = item - 544;
    int nx = it % 50, cy = (it / 50) % 4, b = it / 200;
    int c0 = cy * 64, n0 = nx * 64;
    const bool pad = (n0 >= NcT);
    if (!pad) {
        int ci = t >> 2, nb = (t & 3) * 16;
        const float* src = x + ((size_t)b * Cc + c0 + ci) * NcT + n0 + nb;
#pragma unroll
        for (int k = 0; k < 4; ++k) {
            float4 v = *(const float4*)(src + 4 * k);
            tb[ci][nb + 4 * k + 0] = v.x; tb[ci][nb + 4 * k + 1] = v.y;
            tb[ci][nb + 4 * k + 2] = v.z; tb[ci][nb + 4 * k + 3] = v.w;
        }
    }
    __syncthreads();
    int r = t >> 2, cb = (t & 3) * 16;
    size_t off = ((size_t)b * Np + n0 + r) * 256 + c0 + cb;
    float vv[16];
#pragma unroll
    for (int j = 0; j < 16; ++j) vv[j] = pad ? 0.f : tb[cb + j][r];
    float* dst = out_sm + off;
#pragma unroll
    for (int k = 0; k < 4; ++k) {
        float4 v; v.x = vv[4*k]; v.y = vv[4*k+1]; v.z = vv[4*k+2]; v.w = vv[4*k+3];
        *(float4*)(dst + 4 * k) = v;
    }
    u16x8 h1, h2;
#pragma unroll
    for (int j = 0; j < 8; ++j) { h1[j] = f2bf(vv[j]); h2[j] = f2bf(vv[8 + j]); }
    unsigned short* dh = outh + off;
    *(u16x8*)dh = h1;
    *(u16x8*)(dh + 8) = h2;
}

// dinv[b][i] = d>0 ? rsqrt(d) : 0, d = 0.5*sum_q U[b][i][q]*rs[b][q^128]
__global__ __launch_bounds__(256) void dinv_k(
    const unsigned short* __restrict__ U, const float* __restrict__ rp,
    float* __restrict__ dinv)
{
    __shared__ float rsl[256];
    int b = blockIdx.y, tid = threadIdx.x;
    float s = 0.f;
    for (int j = 0; j < 25; ++j) s += rp[((size_t)b * 25 + j) * 256 + tid];
    rsl[tid ^ 128] = s;
    __syncthreads();
    int i = blockIdx.x * 256 + tid;
    if (i < Np) {
        const unsigned short* row = U + ((size_t)b * Np + i) * 256;
        float acc = 0.f;
        for (int q0 = 0; q0 < 256; q0 += 8) {
            u16x8 v = *(const u16x8*)(row + q0);
#pragma unroll
            for (int j = 0; j < 8; ++j) acc = fmaf(bf2f(v[j]), rsl[q0 + j], acc);
        }
        float d = 0.5f * acc;
        dinv[(size_t)b * Np + i] = d > 0.f ? rsqrtf(d) : 0.f;
    }
}

// Ud[bn][q] = 0.5 * dinv[bn] * U[bn][q]   (1600 blocks x 2048 elems)
__global__ __launch_bounds__(256) void ud_k(
    const unsigned short* __restrict__ U, const float* __restrict__ dinv,
    unsigned short* __restrict__ Ud)
{
    size_t e = ((size_t)blockIdx.x * 256 + threadIdx.x) * 8;
    float sc = 0.5f * dinv[e >> 8];
    u16x8 v = *(const u16x8*)(U + e);
    u16x8 o;
#pragma unroll
    for (int j = 0; j < 8; ++j) o[j] = f2bf(bf2f(v[j]) * sc);
    *(u16x8*)(Ud + e) = o;
}

// BN finalize: 16 blocks x 16 channels; 100 partial groups
__global__ __launch_bounds__(256) void bnfin_k(
    const float* __restrict__ ps, const float* __restrict__ ps2,
    const float* __restrict__ gamma, const float* __restrict__ beta,
    float* __restrict__ scale, float* __restrict__ shift)
{
    __shared__ float l1[256], l2[256];
    int t = threadIdx.x;
    int c = blockIdx.x * 16 + (t & 15);
    int gl = t >> 4;
    float a = 0.f, a2 = 0.f;
    for (int g = gl; g < 100; g += 16) {
        a += ps[(size_t)g * 256 + c];
        a2 += ps2[(size_t)g * 256 + c];
    }
    l1[t] = a; l2[t] = a2;
    __syncthreads();
    if (gl == 0) {
#pragma unroll
        for (int j = 1; j < 16; ++j) {
            a += l1[j * 16 + (t & 15)];
            a2 += l2[j * 16 + (t & 15)];
        }
        const float inv = 1.f / (float)(Bc * NcT);
        float mean = a * inv;
        float var = a2 * inv - mean * mean;
        float sc = gamma[c] * rsqrtf(var + EPSc);
        scale[c] = sc;
        shift[c] = beta[c] - mean * sc;
    }
}

// d_out[b][c][n] = transpose(out_sm + BN(o_sm))   (final stage fused)
__global__ __launch_bounds__(256) void xpoutbn_k(
    const float* __restrict__ out_sm, const unsigned short* __restrict__ oin,
    const float* __restrict__ scale, const float* __restrict__ shift,
    float* __restrict__ outp)
{
    __shared__ float tb[64][65];
    __shared__ float lsc[64], lsh[64];
    int b = blockIdx.z, c0 = blockIdx.y * 64, n0 = blockIdx.x * 64;
    int t = threadIdx.x;
    if (t < 64) { lsc[t] = scale[c0 + t]; lsh[t] = shift[c0 + t]; }
    __syncthreads();
    {
        int r = t >> 2, cb = (t & 3) * 16;
        size_t off = ((size_t)b * Np + n0 + r) * 256 + c0 + cb;
#pragma unroll
        for (int k = 0; k < 2; ++k) {
            float4 a0 = *(const float4*)(out_sm + off + 8 * k);
            float4 a1 = *(const float4*)(out_sm + off + 8 * k + 4);
            u16x8 ov = *(const u16x8*)(oin + off + 8 * k);
            tb[r][cb + 8*k + 0] = a0.x + fmaf(bf2f(ov[0]), lsc[cb + 8*k + 0], lsh[cb + 8*k + 0]);
            tb[r][cb + 8*k + 1] = a0.y + fmaf(bf2f(ov[1]), lsc[cb + 8*k + 1], lsh[cb + 8*k + 1]);
            tb[r][cb + 8*k + 2] = a0.z + fmaf(bf2f(ov[2]), lsc[cb + 8*k + 2], lsh[cb + 8*k + 2]);
            tb[r][cb + 8*k + 3] = a0.w + fmaf(bf2f(ov[3]), lsc[cb + 8*k + 3], lsh[cb + 8*k + 3]);
            tb[r][cb + 8*k + 4] = a1.x + fmaf(bf2f(ov[4]), lsc[cb + 8*k + 4], lsh[cb + 8*k + 4]);
            tb[r][cb + 8*k + 5] = a1.y + fmaf(bf2f(ov[5]), lsc[cb + 8*k + 5], lsh[cb + 8*k + 5]);
            tb[r][cb + 8*k + 6] = a1.z + fmaf(bf2f(ov[6]), lsc[cb + 8*k + 6], lsh[cb + 8*k + 6]);
            tb[r][cb + 8*k + 7] = a1.w + fmaf(bf2f(ov[7]), lsc[cb + 8*k + 7], lsh[cb + 8*k + 7]);
        }
    }
    __syncthreads();
    {
        int c = t >> 2, rb = (t & 3) * 16;
        float vv[16];
#pragma unroll
        for (int j = 0; j < 16; ++j) vv[j] = tb[rb + j][c];
        float* dst = outp + ((size_t)b * Cc + c0 + c) * NcT + n0 + rb;
#pragma unroll
        for (int k = 0; k < 4; ++k) {
            float4 v; v.x = vv[4*k]; v.y = vv[4*k+1]; v.z = vv[4*k+2]; v.w = vv[4*k+3];
            *(float4*)(dst + 4 * k) = v;
        }
    }
}

}  // namespace

extern "C" void kernel_launch(void* const* d_in, const int* in_sizes, int n_in,
                              void* d_out, int out_size, void* d_ws, size_t ws_size,
                              hipStream_t stream) {
    const float* x     = (const float*)d_in[0];
    const float* Wt    = (const float*)d_in[1];
    const float* Wp    = (const float*)d_in[2];
    const float* Wg    = (const float*)d_in[3];
    const float* W1    = (const float*)d_in[4];
    const float* W2    = (const float*)d_in[5];
    const float* gamma = (const float*)d_in[6];
    const float* beta  = (const float*)d_in[7];

    char* p = (char*)d_ws;
    auto alloc = [&](size_t bytes) { char* r = p; p += (bytes + 255) & ~(size_t)255; return r; };
    float*          out_sm = (float*)         alloc((size_t)Bc * Np * 256 * 4);
    unsigned short* outh   = (unsigned short*)alloc((size_t)Bc * Np * 256 * 2);
    unsigned short* U_sm   = (unsigned short*)alloc((size_t)Bc * Np * 256 * 2);
    unsigned short* U_cm   = (unsigned short*)alloc((size_t)Bc * 256 * Np * 2);
    unsigned short* Ud     = (unsigned short*)alloc((size_t)Bc * Np * 256 * 2);
    unsigned short* g_sm   = (unsigned short*)alloc((size_t)Bc * Np * Pc * 2);
    unsigned short* g_cmd  = (unsigned short*)alloc((size_t)Bc * Pc * Np * 2);
    unsigned short* o_sm   = (unsigned short*)alloc((size_t)Bc * Np * 256 * 2);
    unsigned short* Cpart  = (unsigned short*)alloc((size_t)KSn * Bc * 256 * Pc * 2);
    unsigned short* WMb    = (unsigned short*)alloc((size_t)Bc * Cc * 256 * 2);
    unsigned short* Wcomb  = (unsigned short*)alloc((size_t)Cc * Cc * 2);
    unsigned short* Wgh    = (unsigned short*)alloc((size_t)Sc * Pc * Cc * 2);
    unsigned short* W1h    = (unsigned short*)alloc((size_t)Sc * Cc * Pc * 2);
    unsigned short* W2h    = (unsigned short*)alloc((size_t)Sc * Cc * Pc * 2);
    float*          rp     = (float*)         alloc((size_t)100 * 256 * 4);
    float*          dinv   = (float*)         alloc((size_t)Bc * Np * 4);
    float*          ps     = (float*)         alloc((size_t)100 * 256 * 4);
    float*          ps2    = (float*)         alloc((size_t)100 * 256 * 4);
    float*          scale  = (float*)         alloc(256 * 4);
    float*          shiftb = (float*)         alloc(256 * 4);

    const long NpC = (long)Np * 256;
    dim3 blk(256);

    prep_k<<<1344, blk, 0, stream>>>(x, Wt, Wp, Wg, W1, W2,
                                     Wcomb, Wgh, W1h, W2h, out_sm, outh);

    // U = relu([Wt;Wp] @ x): spatial-major + col-major + col sums
    {
        GP g{};
        g.A = outh; g.lda = 256; g.aB = NpC; g.aSl = 0;
        g.Bw = Wcomb; g.ldb = 256; g.bB = 0; g.bSl = 0;
        g.K = 256; g.nsl = 1;
        g.outSM = U_sm; g.ldsm = 256; g.smB = NpC; g.smSlice = 0;
        g.outCM = U_cm; g.cmB = (long)256 * Np;
        g.ps = rp;
        mgemm<128, 1, 1, false, 1, false, false, false>
            <<<dim3(2, 25, Bc), blk, 0, stream>>>(g);
    }

    dinv_k<<<dim3(13, Bc), blk, 0, stream>>>(U_sm, rp, dinv);
    ud_k<<<1600, blk, 0, stream>>>(U_sm, dinv, Ud);

    for (int s = 0; s < Sc; ++s) {
        // g = Wg[s] @ out  (FUSEBN applies previous stage's BN to residual)
        {
            GP g{};
            g.A = outh; g.lda = 256; g.aB = NpC; g.aSl = 0;
            g.Bw = Wgh + (size_t)s * Pc * Cc; g.ldb = 256; g.bB = 0; g.bSl = 0;
            g.K = 256; g.nsl = 1;
            g.outSM = g_sm; g.ldsm = 128; g.smB = (long)Np * 128; g.smSlice = 0;
            g.outCM = g_cmd; g.cmB = (long)Pc * Np;
            g.dinv = dinv;
            g.oin = o_sm; g.bnsc = scale; g.bnsh = shiftb; g.resid = out_sm;
            if (s == 0)
                mgemm<64, 0, 2, false, 0, false, false, false>
                    <<<dim3(1, 50, Bc), blk, 0, stream>>>(g);
            else
                mgemm<64, 0, 2, false, 0, true, false, false>
                    <<<dim3(1, 50, Bc), blk, 0, stream>>>(g);
        }
        // Cpart[ks][b][q^128][p] = partial_i U_cm[q][i] * g_cmd[p][i]
        {
            GP g{};
            g.A = U_cm; g.lda = Np; g.aB = (long)256 * Np; g.aSl = 0;
            g.Bw = g_cmd; g.ldb = Np; g.bB = (long)Pc * Np; g.bSl = 0;
            g.K = Np; g.kchunk = KCH; g.nsl = 1;
            g.outSM = Cpart; g.ldsm = 128; g.smB = (long)256 * Pc;
            g.smSlice = (long)Bc * 256 * Pc;
            mgemm<64, 0, 0, true, 0, false, true, false>
                <<<dim3(1, 4, KSn * Bc), blk, 0, stream>>>(g);
        }
        // WM[b][c][q] = sum_ks sum_p W1[c][p] * Cpart[ks][b][q][p]
        {
            GP g{};
            g.A = W1h + (size_t)s * Cc * Pc; g.lda = 128; g.aB = 0; g.aSl = 0;
            g.Bw = Cpart; g.ldb = 128; g.bB = (long)256 * Pc;
            g.bSl = (long)Bc * 256 * Pc;
            g.K = 128; g.nsl = KSn;
            g.outSM = WMb; g.ldsm = 256; g.smB = (long)Cc * 256; g.smSlice = 0;
            mgemm<64, 0, 0, false, 0, false, false, false>
                <<<dim3(2, 4, Bc), blk, 0, stream>>>(g);
        }
        // o = Ud @ WM^T + g @ W2^T  + BN partial stats
        {
            GP g{};
            g.A = Ud; g.lda = 256; g.aB = NpC; g.aSl = 0;
            g.Bw = WMb; g.ldb = 256; g.bB = (long)Cc * 256; g.bSl = 0;
            g.K = 256; g.nsl = 1;
            g.A2 = g_sm; g.lda2 = 128; g.aB2 = (long)Np * 128;
            g.B2 = W2h + (size_t)s * Cc * Pc; g.ldb2 = 128; g.bB2 = 0;
            g.K2 = 128;
            g.outSM = o_sm; g.ldsm = 256; g.smB = NpC; g.smSlice = 0;
            g.ps = ps; g.ps2 = ps2;
            mgemm<128, 0, 0, false, 2, false, false, true>
                <<<dim3(2, 25, Bc), blk, 0, stream>>>(g);
        }
        bnfin_k<<<16, blk, 0, stream>>>(ps, ps2, gamma + s * Cc, beta + s * Cc,
                                        scale, shiftb);
    }

    // final: d_out = transpose(out_sm + BN(o_sm))
    xpoutbn_k<<<dim3(49, 4, Bc), blk, 0, stream>>>(out_sm, o_sm, scale, shiftb,
                                                   (float*)d_out);
}